// Round 2
// baseline (4705.608 us; speedup 1.0000x reference)
//
#include <hip/hip_runtime.h>

typedef __attribute__((ext_vector_type(8))) short bf16x8;
typedef __attribute__((ext_vector_type(4))) float f32x4;
typedef __attribute__((ext_vector_type(4))) unsigned short u16x4;
typedef __attribute__((ext_vector_type(8))) unsigned short u16x8;

__device__ __forceinline__ unsigned short f2b(float f) {
    unsigned u = __builtin_bit_cast(unsigned, f);
    u += 0x7fffu + ((u >> 16) & 1u);   // round-to-nearest-even
    return (unsigned short)(u >> 16);
}
__device__ __forceinline__ float b2f(unsigned short h) {
    unsigned u = ((unsigned)h) << 16;
    return __builtin_bit_cast(float, u);
}

__global__ void zero_f32(float* __restrict__ p, long total) {
    long i = ((long)blockIdx.x * blockDim.x + threadIdx.x) * 4;
    if (i + 3 < total) {
        *(f32x4*)(p + i) = (f32x4){0.f, 0.f, 0.f, 0.f};
    } else {
        for (long t = i; t < total; ++t) p[t] = 0.f;
    }
}

__global__ void cvt_bf16(const float* __restrict__ x, unsigned short* __restrict__ o, long total) {
    long i = ((long)blockIdx.x * blockDim.x + threadIdx.x) * 4;
    if (i >= total) return;
    f32x4 v = *(const f32x4*)(x + i);
    u16x4 r;
#pragma unroll
    for (int t = 0; t < 4; ++t) r[t] = f2b(v[t]);
    *(u16x4*)(o + i) = r;
}

// Rearrange W [K,128,128] f32 into MFMA-B-fragment-major bf16:
// Wb[k][frag f=kk*8+c][lane][j] = W[k][cin=kk*32+(lane>>4)*8+j][cout=c*16+(lane&15)]
__global__ void prep_w(const float* __restrict__ W1, const float* __restrict__ W2,
                       unsigned short* __restrict__ Wb1, unsigned short* __restrict__ Wb2,
                       int kelems /* K*16384 */) {
    int tid = blockIdx.x * 256 + threadIdx.x;
    if (tid >= 2 * kelems) return;
    int which = (tid >= kelems) ? 1 : 0;
    int rem = which ? (tid - kelems) : tid;
    int k = rem >> 14;
    int r2 = rem & 16383;
    int f = r2 >> 9;
    int lane = (r2 >> 3) & 63;
    int j = r2 & 7;
    int kk = f >> 3, c = f & 7;
    int cin = kk * 32 + (lane >> 4) * 8 + j;
    int cout = c * 16 + (lane & 15);
    const float* W = which ? W2 : W1;
    unsigned short* Wb = which ? Wb2 : Wb1;
    Wb[rem] = f2b(W[(size_t)k * 16384 + cin * 128 + cout]);
}

// One k-slice of the sparse conv: accP[idx_out[k][m]] += xin[idx_in[k][m]] @ W[k]
// accP is a bf16 accumulator in PHYS layout: phys col p = (true&15)*8 + (true>>4).
// block = 512 threads (8 waves), 256 gathered rows per block, 32 per wave.
__global__ __launch_bounds__(512) void conv_mfma(
    const unsigned short* __restrict__ xin,   // [n,128] bf16, true layout
    const unsigned short* __restrict__ Wb,    // [K][32 frags][64 lanes][8] bf16
    const int* __restrict__ idx_in,           // [K,n]
    const int* __restrict__ idx_out,          // [K,n]
    unsigned short* __restrict__ accP,        // [n,128] bf16 accumulator (phys layout)
    int n)
{
    __shared__ unsigned short wlds[16384];    // 32 KB: whole W[k] in frag layout
    const int k = blockIdx.y;
    const int m0 = blockIdx.x * 256;

    {   // stage W[k] -> LDS, coalesced 16B per lane
        const bf16x8* src = (const bf16x8*)(Wb + (size_t)k * 16384);
        bf16x8* dst = (bf16x8*)wlds;
        for (int i = threadIdx.x; i < 2048; i += 512) dst[i] = src[i];
    }
    __syncthreads();

    const int wave = threadIdx.x >> 6;
    const int lane = threadIdx.x & 63;
    const int kg = lane >> 4;     // 0..3
    const int l15 = lane & 15;

    const int* iin  = idx_in  + (size_t)k * n;
    const int* iout = idx_out + (size_t)k * n;
    const int mbase = m0 + wave * 32;

    int arow0, arow1;
    { int m = mbase + l15;      arow0 = (m < n) ? iin[m] : 0; }
    { int m = mbase + 16 + l15; arow1 = (m < n) ? iin[m] : 0; }

    f32x4 acc[2][8];
#pragma unroll
    for (int s = 0; s < 2; ++s)
#pragma unroll
        for (int c = 0; c < 8; ++c) acc[s][c] = (f32x4){0.f, 0.f, 0.f, 0.f};

#pragma unroll
    for (int kk = 0; kk < 4; ++kk) {
        bf16x8 a0 = *(const bf16x8*)(xin + (size_t)arow0 * 128 + kk * 32 + kg * 8);
        bf16x8 a1 = *(const bf16x8*)(xin + (size_t)arow1 * 128 + kk * 32 + kg * 8);
#pragma unroll
        for (int c = 0; c < 8; ++c) {
            bf16x8 b = *(const bf16x8*)(wlds + ((kk * 8 + c) * 64 + lane) * 8);
            acc[0][c] = __builtin_amdgcn_mfma_f32_16x16x32_bf16(a0, b, acc[0][c], 0, 0, 0);
            acc[1][c] = __builtin_amdgcn_mfma_f32_16x16x32_bf16(a1, b, acc[1][c], 0, 0, 0);
        }
    }

    // scatter-add via packed-bf16 atomics.
    // MFMA C/D layout: value acc[s][c][j] is (row m = mbase+s*16+kg*4+j, true col l15+16c).
    // phys col = l15*8 + c, so (c, c+1) pair is memory-adjacent in one lane.
#pragma unroll
    for (int s = 0; s < 2; ++s) {
#pragma unroll
        for (int j = 0; j < 4; ++j) {
            int m = mbase + s * 16 + kg * 4 + j;
            if (m < n) {
                long orow = iout[m];
                unsigned short* base = accP + ((size_t)orow << 7) + (l15 << 3);
#pragma unroll
                for (int cp = 0; cp < 4; ++cp) {
                    unsigned pk;
                    asm("v_cvt_pk_bf16_f32 %0, %1, %2"
                        : "=v"(pk)
                        : "v"(acc[s][2 * cp][j]), "v"(acc[s][2 * cp + 1][j]));
                    unsigned short* p = base + 2 * cp;
                    asm volatile("global_atomic_pk_add_bf16 %0, %1, off"
                                 :: "v"(p), "v"(pk) : "memory");
                }
            }
        }
    }
}

// per-phys-channel sum & sumsq over rows of bf16 phys accumulator
__global__ void bn_stats(const unsigned short* __restrict__ h, float* __restrict__ stats, int n) {
    const int p2 = threadIdx.x & 63;   // col pair: phys cols 2*p2, 2*p2+1
    const int rg = threadIdx.x >> 6;   // 0..3
    const int r0 = blockIdx.x * 256;
    const int rend = min(r0 + 256, n);
    float s0 = 0.f, s20 = 0.f, s1 = 0.f, s21 = 0.f;
    for (int r = r0 + rg; r < rend; r += 4) {
        unsigned u = *(const unsigned*)(h + (size_t)r * 128 + p2 * 2);
        float v0 = b2f((unsigned short)(u & 0xffff));
        float v1 = b2f((unsigned short)(u >> 16));
        s0 += v0; s20 += v0 * v0;
        s1 += v1; s21 += v1 * v1;
    }
    __shared__ float ls[256][4];
    ls[threadIdx.x][0] = s0; ls[threadIdx.x][1] = s20;
    ls[threadIdx.x][2] = s1; ls[threadIdx.x][3] = s21;
    __syncthreads();
    if (rg == 0) {
        float a0 = 0, a1 = 0, a2 = 0, a3 = 0;
#pragma unroll
        for (int g = 0; g < 4; ++g) {
            a0 += ls[g * 64 + p2][0]; a1 += ls[g * 64 + p2][1];
            a2 += ls[g * 64 + p2][2]; a3 += ls[g * 64 + p2][3];
        }
        atomicAdd(&stats[2 * p2], a0);       atomicAdd(&stats[128 + 2 * p2], a1);
        atomicAdd(&stats[2 * p2 + 1], a2);   atomicAdd(&stats[128 + 2 * p2 + 1], a3);
    }
}

// stats indexed by phys channel p; gamma/beta are in true channel order
__global__ void bn_finalize(float* stats, const float* __restrict__ g,
                            const float* __restrict__ b, float inv_n) {
    int p = threadIdx.x;  // 128 threads, phys channel
    int tc = ((p >> 3) & 15) + 16 * (p & 7);
    float mu = stats[p] * inv_n;
    float var = fmaxf(stats[128 + p] * inv_n - mu * mu, 0.f);
    float sc = g[tc] * rsqrtf(var + 1e-5f);
    stats[256 + p] = sc;
    stats[384 + p] = b[tc] - mu * sc;
}

// read phys bf16 acc -> BN+ReLU -> write TRUE-layout bf16 (for conv2 A-gather)
__global__ void bn_relu_bf16(const unsigned short* __restrict__ h, const float* __restrict__ stats,
                             unsigned short* __restrict__ hb, int n) {
    int idx = blockIdx.x * 256 + threadIdx.x;
    int r = idx >> 4;
    int t8 = idx & 15;          // true col group: cols t8*8 .. t8*8+7
    if (r >= n) return;
    const unsigned short* row = h + (size_t)r * 128;
    u16x8 outv;
#pragma unroll
    for (int i = 0; i < 8; ++i) {
        int tc = t8 * 8 + i;
        int p = ((tc & 15) << 3) + (tc >> 4);
        float v = b2f(row[p]);
        float y = fmaxf(v * stats[256 + p] + stats[384 + p], 0.f);
        outv[i] = f2b(y);
    }
    *(u16x8*)(hb + (size_t)r * 128 + t8 * 8) = outv;
}

// read phys bf16 acc + f32 x (true) -> BN + residual + ReLU -> f32 d_out (true)
__global__ void bn_res_relu(const unsigned short* __restrict__ h, const float* __restrict__ stats,
                            const float* __restrict__ x, float* __restrict__ out, int n) {
    int idx = blockIdx.x * 256 + threadIdx.x;
    int r = idx >> 4;
    int t8 = idx & 15;
    if (r >= n) return;
    const unsigned short* row = h + (size_t)r * 128;
    const float* xrow = x + (size_t)r * 128 + t8 * 8;
    float* orow = out + (size_t)r * 128 + t8 * 8;
    f32x4 o0, o1;
    f32x4 x0 = *(const f32x4*)(xrow);
    f32x4 x1 = *(const f32x4*)(xrow + 4);
#pragma unroll
    for (int i = 0; i < 8; ++i) {
        int tc = t8 * 8 + i;
        int p = ((tc & 15) << 3) + (tc >> 4);
        float v = b2f(row[p]);
        float y = v * stats[256 + p] + stats[384 + p];
        y += (i < 4) ? x0[i] : x1[i - 4];
        y = fmaxf(y, 0.f);
        if (i < 4) o0[i] = y; else o1[i - 4] = y;
    }
    *(f32x4*)(orow) = o0;
    *(f32x4*)(orow + 4) = o1;
}

extern "C" void kernel_launch(void* const* d_in, const int* in_sizes, int n_in,
                              void* d_out, int out_size, void* d_ws, size_t ws_size,
                              hipStream_t stream) {
    const float* x  = (const float*)d_in[0];
    const float* W1 = (const float*)d_in[1];
    const float* g1 = (const float*)d_in[2];
    const float* b1 = (const float*)d_in[3];
    const float* W2 = (const float*)d_in[4];
    const float* g2 = (const float*)d_in[5];
    const float* b2 = (const float*)d_in[6];
    const int* idx_in  = (const int*)d_in[7];
    const int* idx_out = (const int*)d_in[8];

    const int n = in_sizes[0] / 128;          // 100000
    const int K = in_sizes[1] / 16384;        // 27
    const long total = (long)n * 128;
    float* out = (float*)d_out;

    // workspace layout (~53 MB):
    // slabA: xb (conv1 input bf16, true) -> later hb (conv2 input bf16, true)
    // slabB: bf16 accumulator (phys layout) for conv1 then conv2
    char* ws = (char*)d_ws;
    unsigned short* slabA = (unsigned short*)ws;                      // n*128 bf16
    unsigned short* slabB = (unsigned short*)(ws + (size_t)total * 2);
    unsigned short* Wb1 = (unsigned short*)(ws + (size_t)total * 4);
    unsigned short* Wb2 = Wb1 + (size_t)K * 16384;
    float* stats = (float*)(Wb2 + (size_t)K * 16384);                 // 2 x 512 f32

    const dim3 b256(256);
    const int gCvt = (int)((total / 4 + 255) / 256);     // 12500
    const int gZeroB = (int)((total / 2 / 4 + 255) / 256);
    const dim3 cgrid((n + 255) / 256, K);
    const dim3 cblk(512);
    const int gRow = (n * 16 + 255) / 256;               // 6250
    const int kelems = K * 16384;

    hipLaunchKernelGGL(zero_f32, dim3(gZeroB), b256, 0, stream, (float*)slabB, total / 2);
    hipLaunchKernelGGL(zero_f32, dim3(1), b256, 0, stream, stats, (long)1024);
    hipLaunchKernelGGL(cvt_bf16, dim3(gCvt), b256, 0, stream, x, slabA, total);
    hipLaunchKernelGGL(prep_w, dim3((2 * kelems + 255) / 256), b256, 0, stream,
                       W1, W2, Wb1, Wb2, kelems);

    // conv1: slabA -> slabB (phys bf16)
    hipLaunchKernelGGL(conv_mfma, cgrid, cblk, 0, stream, slabA, Wb1, idx_in, idx_out, slabB, n);
    hipLaunchKernelGGL(bn_stats, dim3((n + 255) / 256), b256, 0, stream, slabB, stats, n);
    hipLaunchKernelGGL(bn_finalize, dim3(1), dim3(128), 0, stream, stats, g1, b1, 1.0f / n);
    // BN+ReLU: slabB (phys) -> slabA (true bf16), xb is dead now
    hipLaunchKernelGGL(bn_relu_bf16, dim3(gRow), b256, 0, stream, slabB, stats, slabA, n);

    // conv2: slabA -> slabB (re-zeroed)
    hipLaunchKernelGGL(zero_f32, dim3(gZeroB), b256, 0, stream, (float*)slabB, total / 2);
    hipLaunchKernelGGL(conv_mfma, cgrid, cblk, 0, stream, slabA, Wb2, idx_in, idx_out, slabB, n);
    hipLaunchKernelGGL(bn_stats, dim3((n + 255) / 256), b256, 0, stream, slabB, stats + 512, n);
    hipLaunchKernelGGL(bn_finalize, dim3(1), dim3(128), 0, stream, stats + 512, g2, b2, 1.0f / n);
    hipLaunchKernelGGL(bn_res_relu, dim3(gRow), b256, 0, stream, slabB, stats + 512, x, out, n);
}

// Round 3
// 1516.463 us; speedup vs baseline: 3.1030x; 3.1030x over previous
//
#include <hip/hip_runtime.h>

typedef __attribute__((ext_vector_type(8))) short bf16x8;
typedef __attribute__((ext_vector_type(4))) float f32x4;
typedef __attribute__((ext_vector_type(4))) unsigned short u16x4;
typedef __attribute__((ext_vector_type(4))) unsigned u32x4;

__device__ __forceinline__ unsigned short f2b(float f) {
    unsigned u = __builtin_bit_cast(unsigned, f);
    u += 0x7fffu + ((u >> 16) & 1u);   // round-to-nearest-even
    return (unsigned short)(u >> 16);
}

__global__ void zero_f32(float* __restrict__ p, long total) {
    long i = ((long)blockIdx.x * blockDim.x + threadIdx.x) * 4;
    if (i + 3 < total) {
        *(f32x4*)(p + i) = (f32x4){0.f, 0.f, 0.f, 0.f};
    } else {
        for (long t = i; t < total; ++t) p[t] = 0.f;
    }
}

__global__ void cvt_bf16(const float* __restrict__ x, unsigned short* __restrict__ o, long total) {
    long i = ((long)blockIdx.x * blockDim.x + threadIdx.x) * 4;
    if (i >= total) return;
    f32x4 v = *(const f32x4*)(x + i);
    u16x4 r;
#pragma unroll
    for (int t = 0; t < 4; ++t) r[t] = f2b(v[t]);
    *(u16x4*)(o + i) = r;
}

// Rearrange W [K,128,128] f32 into MFMA-B-fragment-major bf16 (layout identical to R1):
// Wb[k][frag f=kk*8+c][lane][j] = W[k][cin=kk*32+(lane>>4)*8+j][cout=c*16+(lane&15)]
__global__ void prep_w(const float* __restrict__ W1, const float* __restrict__ W2,
                       unsigned short* __restrict__ Wb1, unsigned short* __restrict__ Wb2,
                       int kelems) {
    int tid = blockIdx.x * 256 + threadIdx.x;
    if (tid >= 2 * kelems) return;
    int which = (tid >= kelems) ? 1 : 0;
    int rem = which ? (tid - kelems) : tid;
    int k = rem >> 14;
    int r2 = rem & 16383;
    int f = r2 >> 9;
    int lane = (r2 >> 3) & 63;
    int j = r2 & 7;
    int kk = f >> 3, c = f & 7;
    int cin = kk * 32 + (lane >> 4) * 8 + j;
    int cout = c * 16 + (lane & 15);
    const float* W = which ? W2 : W1;
    unsigned short* Wb = which ? Wb2 : Wb1;
    Wb[rem] = f2b(W[(size_t)k * 16384 + cin * 128 + cout]);
}

// ---------------- CSR build (invert idx_out; shared by both convs) ----------------

__global__ void hist_k(const int* __restrict__ io, int* __restrict__ cnt,
                       int nk, int gsn, int G) {
    int t = blockIdx.x * 256 + threadIdx.x;
    if (t >= nk) return;
    int r = io[t];
    int g = (G == 1) ? 0 : (t / gsn);
    atomicAdd(&cnt[r * G + g], 1);
}

__global__ void scan_part(const int* __restrict__ cnt, int* __restrict__ bsum, int nbins) {
    __shared__ int ls[256];
    int base = blockIdx.x * 4096 + threadIdx.x * 16;
    int s = 0;
#pragma unroll
    for (int i = 0; i < 16; ++i) { int idx = base + i; if (idx < nbins) s += cnt[idx]; }
    ls[threadIdx.x] = s; __syncthreads();
    for (int o = 128; o > 0; o >>= 1) {
        if ((int)threadIdx.x < o) ls[threadIdx.x] += ls[threadIdx.x + o];
        __syncthreads();
    }
    if (threadIdx.x == 0) bsum[blockIdx.x] = ls[0];
}

__global__ void scan_bsum(int* __restrict__ bsum, int nb, int* __restrict__ row_ptr, int nbins) {
    if (threadIdx.x == 0 && blockIdx.x == 0) {
        int run = 0;
        for (int i = 0; i < nb; ++i) { int t = bsum[i]; bsum[i] = run; run += t; }
        row_ptr[nbins] = run;
    }
}

__global__ void scan_final(const int* __restrict__ cnt, const int* __restrict__ bsum,
                           int* __restrict__ row_ptr, int* __restrict__ pos, int nbins) {
    __shared__ int ls[256];
    const int tid = threadIdx.x;
    int base = blockIdx.x * 4096 + tid * 16;
    int loc[16];
    int s = 0;
#pragma unroll
    for (int i = 0; i < 16; ++i) {
        int idx = base + i;
        int v = (idx < nbins) ? cnt[idx] : 0;
        loc[i] = s; s += v;
    }
    ls[tid] = s; __syncthreads();
    for (int o = 1; o < 256; o <<= 1) {
        int add = (tid >= o) ? ls[tid - o] : 0;
        __syncthreads();
        ls[tid] += add;
        __syncthreads();
    }
    int excl = ls[tid] - s + bsum[blockIdx.x];
#pragma unroll
    for (int i = 0; i < 16; ++i) {
        int idx = base + i;
        if (idx < nbins) { int v = excl + loc[i]; row_ptr[idx] = v; pos[idx] = v; }
    }
}

__global__ void fill_k(const int* __restrict__ io, int* __restrict__ pos,
                       int* __restrict__ cidx, int nk, int gsn, int G) {
    int t = blockIdx.x * 256 + threadIdx.x;
    if (t >= nk) return;
    int r = io[t];
    int g = (G == 1) ? 0 : (t / gsn);
    int p = atomicAdd(&pos[r * G + g], 1);
    cidx[p] = t - g * gsn;     // row index within this group's y slab
}

// ---------------- Phase A: gathered GEMM, linear bf16 y rows (phys-packed) ----------------
// y row layout: 64 u32; u32 at index l*4+cp holds true cols (l + 16*(2cp), l + 16*(2cp+1)).
__global__ __launch_bounds__(512) void gemm_y(
    const unsigned short* __restrict__ xin,   // [n,128] bf16, true layout
    const unsigned short* __restrict__ Wb,    // group base: [ks][32 frags][64 lanes][8]
    const int* __restrict__ idx_in,           // group base: [ks, n]
    unsigned* __restrict__ yu,                // [ks*n, 64] u32
    int n)
{
    __shared__ unsigned short wlds[16384];
    const int k = blockIdx.y;                 // local k within group
    const int m0 = blockIdx.x * 256;

    {
        const bf16x8* src = (const bf16x8*)(Wb + (size_t)k * 16384);
        bf16x8* dst = (bf16x8*)wlds;
        for (int i = threadIdx.x; i < 2048; i += 512) dst[i] = src[i];
    }
    __syncthreads();

    const int wave = threadIdx.x >> 6;
    const int lane = threadIdx.x & 63;
    const int kg = lane >> 4;
    const int l15 = lane & 15;

    const int* iin = idx_in + (size_t)k * n;
    const int mbase = m0 + wave * 32;

    int arow0, arow1;
    { int m = mbase + l15;      arow0 = (m < n) ? iin[m] : 0; }
    { int m = mbase + 16 + l15; arow1 = (m < n) ? iin[m] : 0; }

    f32x4 acc[2][8];
#pragma unroll
    for (int s = 0; s < 2; ++s)
#pragma unroll
        for (int c = 0; c < 8; ++c) acc[s][c] = (f32x4){0.f, 0.f, 0.f, 0.f};

#pragma unroll
    for (int kk = 0; kk < 4; ++kk) {
        bf16x8 a0 = *(const bf16x8*)(xin + (size_t)arow0 * 128 + kk * 32 + kg * 8);
        bf16x8 a1 = *(const bf16x8*)(xin + (size_t)arow1 * 128 + kk * 32 + kg * 8);
#pragma unroll
        for (int c = 0; c < 8; ++c) {
            bf16x8 b = *(const bf16x8*)(wlds + ((kk * 8 + c) * 64 + lane) * 8);
            acc[0][c] = __builtin_amdgcn_mfma_f32_16x16x32_bf16(a0, b, acc[0][c], 0, 0, 0);
            acc[1][c] = __builtin_amdgcn_mfma_f32_16x16x32_bf16(a1, b, acc[1][c], 0, 0, 0);
        }
    }

    // write contribution rows linearly (value acc[s][c][j]: row mbase+s*16+kg*4+j, true col l15+16c)
#pragma unroll
    for (int s = 0; s < 2; ++s) {
#pragma unroll
        for (int j = 0; j < 4; ++j) {
            int m = mbase + s * 16 + kg * 4 + j;
            if (m < n) {
                u32x4 v;
#pragma unroll
                for (int cp = 0; cp < 4; ++cp) {
                    unsigned pk;
                    asm("v_cvt_pk_bf16_f32 %0, %1, %2"
                        : "=v"(pk)
                        : "v"(acc[s][2 * cp][j]), "v"(acc[s][2 * cp + 1][j]));
                    v[cp] = pk;
                }
                u32x4* dst = (u32x4*)(yu + ((size_t)k * n + m) * 64 + l15 * 4);
                __builtin_nontemporal_store(v, dst);
            }
        }
    }
}

// ---------------- Phase B: per-output-row segment reduce (no atomics) ----------------
// lane l accumulates the u32 at column l of each contribution row: true cols tc0=(l>>2)+32*(l&3), tc0+16.
__global__ __launch_bounds__(256) void reduce_y(
    const unsigned* __restrict__ yu, const int* __restrict__ row_ptr,
    const int* __restrict__ cidx, float* __restrict__ acc,
    int n, int G, int g, int first)
{
    const int w = threadIdx.x >> 6, l = threadIdx.x & 63;
    const int r = blockIdx.x * 4 + w;
    if (r >= n) return;
    int e = row_ptr[r * G + g];
    const int e1 = row_ptr[r * G + g + 1];

    float a0 = 0.f, a1 = 0.f;
    for (; e + 4 <= e1; e += 4) {
        int t0 = cidx[e], t1 = cidx[e + 1], t2 = cidx[e + 2], t3 = cidx[e + 3];
        unsigned v0 = __builtin_nontemporal_load(yu + (size_t)t0 * 64 + l);
        unsigned v1 = __builtin_nontemporal_load(yu + (size_t)t1 * 64 + l);
        unsigned v2 = __builtin_nontemporal_load(yu + (size_t)t2 * 64 + l);
        unsigned v3 = __builtin_nontemporal_load(yu + (size_t)t3 * 64 + l);
        a0 += __builtin_bit_cast(float, v0 << 16) + __builtin_bit_cast(float, v1 << 16)
            + __builtin_bit_cast(float, v2 << 16) + __builtin_bit_cast(float, v3 << 16);
        a1 += __builtin_bit_cast(float, v0 & 0xffff0000u) + __builtin_bit_cast(float, v1 & 0xffff0000u)
            + __builtin_bit_cast(float, v2 & 0xffff0000u) + __builtin_bit_cast(float, v3 & 0xffff0000u);
    }
    for (; e < e1; ++e) {
        int t = cidx[e];
        unsigned v = __builtin_nontemporal_load(yu + (size_t)t * 64 + l);
        a0 += __builtin_bit_cast(float, v << 16);
        a1 += __builtin_bit_cast(float, v & 0xffff0000u);
    }
    const int tc0 = (l >> 2) + 32 * (l & 3);
    float* dst = acc + (size_t)r * 128 + tc0;
    if (first) { dst[0] = a0; dst[16] = a1; }
    else       { dst[0] += a0; dst[16] += a1; }
}

// ---------------- Fallback: R1 atomic conv (true-layout f32 acc) ----------------
__global__ __launch_bounds__(512) void conv_atomic(
    const unsigned short* __restrict__ xin, const unsigned short* __restrict__ Wb,
    const int* __restrict__ idx_in, const int* __restrict__ idx_out,
    float* __restrict__ out, int n)
{
    __shared__ unsigned short wlds[16384];
    const int k = blockIdx.y;
    const int m0 = blockIdx.x * 256;
    {
        const bf16x8* src = (const bf16x8*)(Wb + (size_t)k * 16384);
        bf16x8* dst = (bf16x8*)wlds;
        for (int i = threadIdx.x; i < 2048; i += 512) dst[i] = src[i];
    }
    __syncthreads();
    const int wave = threadIdx.x >> 6;
    const int lane = threadIdx.x & 63;
    const int kg = lane >> 4;
    const int l15 = lane & 15;
    const int* iin  = idx_in  + (size_t)k * n;
    const int* iout = idx_out + (size_t)k * n;
    const int mbase = m0 + wave * 32;
    int arow0, arow1;
    { int m = mbase + l15;      arow0 = (m < n) ? iin[m] : 0; }
    { int m = mbase + 16 + l15; arow1 = (m < n) ? iin[m] : 0; }
    f32x4 acc[2][8];
#pragma unroll
    for (int s = 0; s < 2; ++s)
#pragma unroll
        for (int c = 0; c < 8; ++c) acc[s][c] = (f32x4){0.f, 0.f, 0.f, 0.f};
#pragma unroll
    for (int kk = 0; kk < 4; ++kk) {
        bf16x8 a0 = *(const bf16x8*)(xin + (size_t)arow0 * 128 + kk * 32 + kg * 8);
        bf16x8 a1 = *(const bf16x8*)(xin + (size_t)arow1 * 128 + kk * 32 + kg * 8);
#pragma unroll
        for (int c = 0; c < 8; ++c) {
            bf16x8 b = *(const bf16x8*)(wlds + ((kk * 8 + c) * 64 + lane) * 8);
            acc[0][c] = __builtin_amdgcn_mfma_f32_16x16x32_bf16(a0, b, acc[0][c], 0, 0, 0);
            acc[1][c] = __builtin_amdgcn_mfma_f32_16x16x32_bf16(a1, b, acc[1][c], 0, 0, 0);
        }
    }
#pragma unroll
    for (int s = 0; s < 2; ++s)
#pragma unroll
        for (int j = 0; j < 4; ++j) {
            int m = mbase + s * 16 + kg * 4 + j;
            if (m < n) {
                long orow = iout[m];
                float* dst = out + orow * 128 + l15;
#pragma unroll
                for (int c = 0; c < 8; ++c) atomicAdd(dst + c * 16, acc[s][c][j]);
            }
        }
}

// ---------------- BN epilogues (true layout, f32 acc) ----------------

__global__ void bn_stats(const float* __restrict__ h, float* __restrict__ stats, int n) {
    const int c = threadIdx.x & 127;
    const int half = threadIdx.x >> 7;
    const int r0 = blockIdx.x * 256;
    const int rend = min(r0 + 256, n);
    float s = 0.f, s2 = 0.f;
    for (int r = r0 + half; r < rend; r += 2) {
        float v = h[(size_t)r * 128 + c];
        s += v; s2 += v * v;
    }
    __shared__ float ls[256], ls2[256];
    ls[threadIdx.x] = s; ls2[threadIdx.x] = s2;
    __syncthreads();
    if (half == 0) {
        atomicAdd(&stats[c], ls[c] + ls[128 + c]);
        atomicAdd(&stats[128 + c], ls2[c] + ls2[128 + c]);
    }
}

__global__ void bn_finalize(float* stats, const float* __restrict__ g,
                            const float* __restrict__ b, float inv_n) {
    int c = threadIdx.x;  // 128 threads
    float mu = stats[c] * inv_n;
    float var = fmaxf(stats[128 + c] * inv_n - mu * mu, 0.f);
    float sc = g[c] * rsqrtf(var + 1e-5f);
    stats[256 + c] = sc;
    stats[384 + c] = b[c] - mu * sc;
}

__global__ void bn_relu_bf16(const float* __restrict__ h, const float* __restrict__ stats,
                             unsigned short* __restrict__ hb, long total) {
    long i = ((long)blockIdx.x * 256 + threadIdx.x) * 4;
    if (i >= total) return;
    int c = (int)(i & 127);
    f32x4 v = *(const f32x4*)(h + i);
    u16x4 r;
#pragma unroll
    for (int t = 0; t < 4; ++t) {
        float y = fmaxf(v[t] * stats[256 + c + t] + stats[384 + c + t], 0.f);
        r[t] = f2b(y);
    }
    *(u16x4*)(hb + i) = r;
}

__global__ void bn_res_relu(float* __restrict__ out, const float* __restrict__ stats,
                            const float* __restrict__ x, long total) {
    long i = ((long)blockIdx.x * 256 + threadIdx.x) * 4;
    if (i >= total) return;
    int c = (int)(i & 127);
    f32x4 h = *(const f32x4*)(out + i);
    f32x4 xv = *(const f32x4*)(x + i);
    f32x4 r;
#pragma unroll
    for (int t = 0; t < 4; ++t)
        r[t] = fmaxf(h[t] * stats[256 + c + t] + stats[384 + c + t] + xv[t], 0.f);
    *(f32x4*)(out + i) = r;
}

extern "C" void kernel_launch(void* const* d_in, const int* in_sizes, int n_in,
                              void* d_out, int out_size, void* d_ws, size_t ws_size,
                              hipStream_t stream) {
    const float* x  = (const float*)d_in[0];
    const float* W1 = (const float*)d_in[1];
    const float* g1 = (const float*)d_in[2];
    const float* b1 = (const float*)d_in[3];
    const float* W2 = (const float*)d_in[4];
    const float* g2 = (const float*)d_in[5];
    const float* b2 = (const float*)d_in[6];
    const int* idx_in  = (const int*)d_in[7];
    const int* idx_out = (const int*)d_in[8];

    const int n = in_sizes[0] / 128;
    const int K = in_sizes[1] / 16384;
    const long total = (long)n * 128;
    const int nk = K * n;
    float* acc = (float*)d_out;              // f32 accumulator lives in d_out (R1-proven)

    // ---- adaptive workspace layout ----
    char* ws = (char*)d_ws;
    size_t off = 0;
    auto alloc = [&](size_t bytes) { size_t o = off; off = (off + bytes + 255) & ~255ULL; return o; };
    const size_t o_slabA = alloc((size_t)total * 2);
    const size_t o_Wb1   = alloc((size_t)K * 16384 * 2);
    const size_t o_Wb2   = alloc((size_t)K * 16384 * 2);
    const size_t o_stats = alloc(1024 * 4);
    const size_t o_cidx  = alloc((size_t)nk * 4);
    const size_t fixed_end = off;

    int G = -1, gs = 0;
    size_t o_cnt = 0, o_ptr = 0, o_pos = 0, o_bsum = 0, o_y = 0;
    for (int gss = K; gss >= 1; --gss) {     // largest group first
        int gc = (K + gss - 1) / gss;
        size_t nbins = (size_t)n * gc;
        size_t nb = (nbins + 4095) / 4096;
        size_t need = fixed_end;
        size_t t_cnt  = (need + nbins * 4 + 255) & ~255ULL;        need = t_cnt;
        size_t t_ptr  = (need + (nbins + 1) * 4 + 255) & ~255ULL;  need = t_ptr;
        size_t t_pos  = (need + nbins * 4 + 255) & ~255ULL;        need = t_pos;
        size_t t_bs   = (need + (nb + 2) * 4 + 255) & ~255ULL;     need = t_bs;
        size_t t_y    = need + (size_t)gss * total * 2;
        if (t_y <= ws_size) {
            G = gc; gs = gss;
            o_cnt = fixed_end;
            o_ptr = t_cnt - ((nbins + 1) * 4 + 255 & ~255ULL) + 0; // recompute cleanly below
            break;
        }
    }

    unsigned short* slabA = (unsigned short*)(ws + o_slabA);
    unsigned short* Wb1   = (unsigned short*)(ws + o_Wb1);
    unsigned short* Wb2   = (unsigned short*)(ws + o_Wb2);
    float* stats          = (float*)(ws + o_stats);
    int* cidx             = (int*)(ws + o_cidx);

    const dim3 b256(256);
    const int gCvt = (int)((total / 4 + 255) / 256);
    const int gAcc = (int)((total / 4 + 255) / 256);
    const int kelems = K * 16384;

    // common prologue
    hipLaunchKernelGGL(zero_f32, dim3(1), b256, 0, stream, stats, (long)1024);
    hipLaunchKernelGGL(cvt_bf16, dim3(gCvt), b256, 0, stream, x, slabA, total);
    hipLaunchKernelGGL(prep_w, dim3((2 * kelems + 255) / 256), b256, 0, stream,
                       W1, W2, Wb1, Wb2, kelems);

    if (G > 0) {
        // recompute offsets for the chosen G (clean pass)
        size_t nbins = (size_t)n * G;
        size_t nb = (nbins + 4095) / 4096;
        off = fixed_end;
        o_cnt  = alloc(nbins * 4);
        o_ptr  = alloc((nbins + 1) * 4);
        o_pos  = alloc(nbins * 4);
        o_bsum = alloc((nb + 2) * 4);
        o_y    = alloc((size_t)gs * total * 2);
        int* cnt     = (int*)(ws + o_cnt);
        int* row_ptr = (int*)(ws + o_ptr);
        int* pos     = (int*)(ws + o_pos);
        int* bsum    = (int*)(ws + o_bsum);
        unsigned* yu = (unsigned*)(ws + o_y);
        const int gsn = gs * n;

        // CSR build (once, shared by both convs)
        hipLaunchKernelGGL(zero_f32, dim3((int)((nbins / 4 + 255) / 256) + 1), b256, 0, stream,
                           (float*)cnt, (long)nbins);
        hipLaunchKernelGGL(hist_k, dim3((nk + 255) / 256), b256, 0, stream,
                           idx_out, cnt, nk, gsn, G);
        hipLaunchKernelGGL(scan_part, dim3((int)nb), b256, 0, stream, cnt, bsum, (int)nbins);
        hipLaunchKernelGGL(scan_bsum, dim3(1), dim3(64), 0, stream, bsum, (int)nb, row_ptr, (int)nbins);
        hipLaunchKernelGGL(scan_final, dim3((int)nb), b256, 0, stream, cnt, bsum, row_ptr, pos, (int)nbins);
        hipLaunchKernelGGL(fill_k, dim3((nk + 255) / 256), b256, 0, stream,
                           idx_out, pos, cidx, nk, gsn, G);

        for (int conv = 0; conv < 2; ++conv) {
            const unsigned short* Wb = conv ? Wb2 : Wb1;
            float* st = stats + conv * 512;
            for (int g = 0; g < G; ++g) {
                int ks = min(gs, K - g * gs);
                hipLaunchKernelGGL(gemm_y, dim3((n + 255) / 256, ks), dim3(512), 0, stream,
                                   slabA, Wb + (size_t)g * gs * 16384,
                                   idx_in + (size_t)g * gsn, yu, n);
                hipLaunchKernelGGL(reduce_y, dim3((n + 3) / 4), b256, 0, stream,
                                   yu, row_ptr, cidx, acc, n, G, g, (g == 0) ? 1 : 0);
            }
            hipLaunchKernelGGL(bn_stats, dim3((n + 255) / 256), b256, 0, stream, acc, st, n);
            hipLaunchKernelGGL(bn_finalize, dim3(1), dim3(128), 0, stream, st,
                               conv ? g2 : g1, conv ? b2 : b1, 1.0f / n);
            if (conv == 0)
                hipLaunchKernelGGL(bn_relu_bf16, dim3(gCvt), b256, 0, stream, acc, st, slabA, total);
            else
                hipLaunchKernelGGL(bn_res_relu, dim3(gAcc), b256, 0, stream, acc, st, x, total);
        }
    } else {
        // atomic fallback (R1 path)
        for (int conv = 0; conv < 2; ++conv) {
            const unsigned short* Wb = conv ? Wb2 : Wb1;
            float* st = stats + conv * 512;
            hipLaunchKernelGGL(zero_f32, dim3(gAcc), b256, 0, stream, acc, total);
            hipLaunchKernelGGL(conv_atomic, dim3((n + 255) / 256, K), dim3(512), 0, stream,
                               slabA, Wb, idx_in, idx_out, acc, n);
            hipLaunchKernelGGL(bn_stats, dim3((n + 255) / 256), b256, 0, stream, acc, st, n);
            hipLaunchKernelGGL(bn_finalize, dim3(1), dim3(128), 0, stream, st,
                               conv ? g2 : g1, conv ? b2 : b1, 1.0f / n);
            if (conv == 0)
                hipLaunchKernelGGL(bn_relu_bf16, dim3(gCvt), b256, 0, stream, acc, st, slabA, total);
            else
                hipLaunchKernelGGL(bn_res_relu, dim3(gAcc), b256, 0, stream, acc, st, x, total);
        }
    }
}

// Round 4
// 1432.343 us; speedup vs baseline: 3.2853x; 1.0587x over previous
//
#include <hip/hip_runtime.h>

typedef __attribute__((ext_vector_type(8))) short bf16x8;
typedef __attribute__((ext_vector_type(4))) float f32x4;
typedef __attribute__((ext_vector_type(4))) unsigned short u16x4;
typedef __attribute__((ext_vector_type(4))) unsigned u32x4;

__device__ __forceinline__ unsigned short f2b(float f) {
    unsigned u = __builtin_bit_cast(unsigned, f);
    u += 0x7fffu + ((u >> 16) & 1u);   // round-to-nearest-even
    return (unsigned short)(u >> 16);
}

__global__ void zero_f32(float* __restrict__ p, long total) {
    long i = ((long)blockIdx.x * blockDim.x + threadIdx.x) * 4;
    if (i + 3 < total) {
        *(f32x4*)(p + i) = (f32x4){0.f, 0.f, 0.f, 0.f};
    } else {
        for (long t = i; t < total; ++t) p[t] = 0.f;
    }
}

__global__ void cvt_bf16(const float* __restrict__ x, unsigned short* __restrict__ o, long total) {
    long i = ((long)blockIdx.x * blockDim.x + threadIdx.x) * 4;
    if (i >= total) return;
    f32x4 v = *(const f32x4*)(x + i);
    u16x4 r;
#pragma unroll
    for (int t = 0; t < 4; ++t) r[t] = f2b(v[t]);
    *(u16x4*)(o + i) = r;
}

// Wb[k][frag f=kk*8+c][lane][j] = W[k][cin=kk*32+(lane>>4)*8+j][cout=c*16+(lane&15)]
__global__ void prep_w(const float* __restrict__ W1, const float* __restrict__ W2,
                       unsigned short* __restrict__ Wb1, unsigned short* __restrict__ Wb2,
                       int kelems) {
    int tid = blockIdx.x * 256 + threadIdx.x;
    if (tid >= 2 * kelems) return;
    int which = (tid >= kelems) ? 1 : 0;
    int rem = which ? (tid - kelems) : tid;
    int k = rem >> 14;
    int r2 = rem & 16383;
    int f = r2 >> 9;
    int lane = (r2 >> 3) & 63;
    int j = r2 & 7;
    int kk = f >> 3, c = f & 7;
    int cin = kk * 32 + (lane >> 4) * 8 + j;
    int cout = c * 16 + (lane & 15);
    const float* W = which ? W2 : W1;
    unsigned short* Wb = which ? Wb2 : Wb1;
    Wb[rem] = f2b(W[(size_t)k * 16384 + cin * 128 + cout]);
}

// ---------------- CSR build: bins are g-major (bin = g*n + r) ----------------

__global__ void hist_k(const int* __restrict__ io, int* __restrict__ cnt,
                       int nk, int gsn, int n, int G) {
    int t = blockIdx.x * 256 + threadIdx.x;
    if (t >= nk) return;
    int r = io[t];
    int g = (G == 1) ? 0 : (t / gsn);
    atomicAdd(&cnt[(size_t)g * n + r], 1);
}

__global__ void scan_part(const int* __restrict__ cnt, int* __restrict__ bsum, int nbins) {
    __shared__ int ls[256];
    int base = blockIdx.x * 4096 + threadIdx.x * 16;
    int s = 0;
#pragma unroll
    for (int i = 0; i < 16; ++i) { int idx = base + i; if (idx < nbins) s += cnt[idx]; }
    ls[threadIdx.x] = s; __syncthreads();
    for (int o = 128; o > 0; o >>= 1) {
        if ((int)threadIdx.x < o) ls[threadIdx.x] += ls[threadIdx.x + o];
        __syncthreads();
    }
    if (threadIdx.x == 0) bsum[blockIdx.x] = ls[0];
}

__global__ void scan_bsum(int* __restrict__ bsum, int nb, int* __restrict__ row_ptr, int nbins) {
    if (threadIdx.x == 0 && blockIdx.x == 0) {
        int run = 0;
        for (int i = 0; i < nb; ++i) { int t = bsum[i]; bsum[i] = run; run += t; }
        row_ptr[nbins] = run;
    }
}

__global__ void scan_final(const int* __restrict__ cnt, const int* __restrict__ bsum,
                           int* __restrict__ row_ptr, int* __restrict__ pos, int nbins) {
    __shared__ int ls[256];
    const int tid = threadIdx.x;
    int base = blockIdx.x * 4096 + tid * 16;
    int loc[16];
    int s = 0;
#pragma unroll
    for (int i = 0; i < 16; ++i) {
        int idx = base + i;
        int v = (idx < nbins) ? cnt[idx] : 0;
        loc[i] = s; s += v;
    }
    ls[tid] = s; __syncthreads();
    for (int o = 1; o < 256; o <<= 1) {
        int add = (tid >= o) ? ls[tid - o] : 0;
        __syncthreads();
        ls[tid] += add;
        __syncthreads();
    }
    int excl = ls[tid] - s + bsum[blockIdx.x];
#pragma unroll
    for (int i = 0; i < 16; ++i) {
        int idx = base + i;
        if (idx < nbins) { int v = excl + loc[i]; row_ptr[idx] = v; pos[idx] = v; }
    }
}

// slot[t] = group-local CSR position of contribution t. LINEAR write (no scatter).
__global__ void fill_slot(const int* __restrict__ io, int* __restrict__ pos,
                          int* __restrict__ slot, int nk, int gsn, int n, int G) {
    int t = blockIdx.x * 256 + threadIdx.x;
    if (t >= nk) return;
    int r = io[t];
    int g = (G == 1) ? 0 : (t / gsn);
    int p = atomicAdd(&pos[(size_t)g * n + r], 1);
    slot[t] = p - g * gsn;
}

// ---------------- Phase A: gathered GEMM -> y rows at CSR slots ----------------
// y row = 64 u32; u32 index w=(l15*4+cp) holds true cols (l15+32cp, l15+32cp+16).
__global__ __launch_bounds__(512) void gemm_y(
    const unsigned short* __restrict__ xin,   // [n,128] bf16 true layout
    const unsigned short* __restrict__ Wb,    // group base
    const int* __restrict__ idx_in,           // group base [ks,n]
    const int* __restrict__ slot,             // group base [ks*n], local positions
    unsigned* __restrict__ yu,                // [gs*n, 64]
    int n)
{
    __shared__ unsigned short wlds[16384];
    __shared__ int sslot[256];
    const int k = blockIdx.y;
    const int m0 = blockIdx.x * 256;

    {
        const bf16x8* src = (const bf16x8*)(Wb + (size_t)k * 16384);
        bf16x8* dst = (bf16x8*)wlds;
        for (int i = threadIdx.x; i < 2048; i += 512) dst[i] = src[i];
        if (threadIdx.x < 256) {
            int m = m0 + threadIdx.x;
            sslot[threadIdx.x] = (m < n) ? slot[(size_t)k * n + m] : 0;
        }
    }
    __syncthreads();

    const int wave = threadIdx.x >> 6;
    const int lane = threadIdx.x & 63;
    const int kg = lane >> 4;
    const int l15 = lane & 15;

    const int* iin = idx_in + (size_t)k * n;
    const int mbase = m0 + wave * 32;

    int arow0, arow1;
    { int m = mbase + l15;      arow0 = (m < n) ? iin[m] : 0; }
    { int m = mbase + 16 + l15; arow1 = (m < n) ? iin[m] : 0; }

    f32x4 acc[2][8];
#pragma unroll
    for (int s = 0; s < 2; ++s)
#pragma unroll
        for (int c = 0; c < 8; ++c) acc[s][c] = (f32x4){0.f, 0.f, 0.f, 0.f};

#pragma unroll
    for (int kk = 0; kk < 4; ++kk) {
        bf16x8 a0 = *(const bf16x8*)(xin + (size_t)arow0 * 128 + kk * 32 + kg * 8);
        bf16x8 a1 = *(const bf16x8*)(xin + (size_t)arow1 * 128 + kk * 32 + kg * 8);
#pragma unroll
        for (int c = 0; c < 8; ++c) {
            bf16x8 b = *(const bf16x8*)(wlds + ((kk * 8 + c) * 64 + lane) * 8);
            acc[0][c] = __builtin_amdgcn_mfma_f32_16x16x32_bf16(a0, b, acc[0][c], 0, 0, 0);
            acc[1][c] = __builtin_amdgcn_mfma_f32_16x16x32_bf16(a1, b, acc[1][c], 0, 0, 0);
        }
    }

    // value acc[s][c][j]: gathered row m = mbase+s*16+kg*4+j, true col l15+16c
#pragma unroll
    for (int s = 0; s < 2; ++s) {
#pragma unroll
        for (int j = 0; j < 4; ++j) {
            int m = mbase + s * 16 + kg * 4 + j;
            if (m < n) {
                u32x4 v;
#pragma unroll
                for (int cp = 0; cp < 4; ++cp) {
                    unsigned pk;
                    asm("v_cvt_pk_bf16_f32 %0, %1, %2"
                        : "=v"(pk)
                        : "v"(acc[s][2 * cp][j]), "v"(acc[s][2 * cp + 1][j]));
                    v[cp] = pk;
                }
                int p = sslot[m - m0];
                u32x4* dst = (u32x4*)(yu + (size_t)p * 64 + l15 * 4);
                __builtin_nontemporal_store(v, dst);
            }
        }
    }
}

// ---------------- Phase B: contiguous segment reduce + fused BN stats ----------------
// lane l owns u32 column l: true cols tc0 = (l>>2)+32*(l&3) and tc0+16.
__global__ __launch_bounds__(256) void reduce_y(
    const unsigned* __restrict__ yu,
    const int* __restrict__ rp,        // row_ptr + g*n
    float* __restrict__ hbuf,          // [n,128] f32, true layout
    float* __restrict__ stats,
    int n, int base, int accum, int do_stats)
{
    const int w = threadIdx.x >> 6, l = threadIdx.x & 63;
    const int tc0 = (l >> 2) + 32 * (l & 3);
    float s0 = 0.f, q0 = 0.f, s1 = 0.f, q1 = 0.f;

    for (int r = blockIdx.x * 4 + w; r < n; r += gridDim.x * 4) {
        int e = rp[r] - base;
        const int e1 = rp[r + 1] - base;
        float a0 = 0.f, a1 = 0.f;
        for (; e < e1; ++e) {
            unsigned v = __builtin_nontemporal_load(yu + (size_t)e * 64 + l);
            a0 += __builtin_bit_cast(float, v << 16);
            a1 += __builtin_bit_cast(float, v & 0xffff0000u);
        }
        float* dst = hbuf + (size_t)r * 128 + tc0;
        if (accum) { a0 += dst[0]; a1 += dst[16]; }
        dst[0] = a0; dst[16] = a1;
        s0 += a0; q0 += a0 * a0; s1 += a1; q1 += a1 * a1;
    }

    if (do_stats) {
        __shared__ float ls[4][64][4];
        ls[w][l][0] = s0; ls[w][l][1] = q0; ls[w][l][2] = s1; ls[w][l][3] = q1;
        __syncthreads();
        if (w == 0) {
            float t0 = 0, t1 = 0, t2 = 0, t3 = 0;
#pragma unroll
            for (int ww = 0; ww < 4; ++ww) {
                t0 += ls[ww][l][0]; t1 += ls[ww][l][1];
                t2 += ls[ww][l][2]; t3 += ls[ww][l][3];
            }
            atomicAdd(&stats[tc0], t0);       atomicAdd(&stats[128 + tc0], t1);
            atomicAdd(&stats[tc0 + 16], t2);  atomicAdd(&stats[128 + tc0 + 16], t3);
        }
    }
}

// ---------------- Fallback: atomic conv (R1) ----------------
__global__ __launch_bounds__(512) void conv_atomic(
    const unsigned short* __restrict__ xin, const unsigned short* __restrict__ Wb,
    const int* __restrict__ idx_in, const int* __restrict__ idx_out,
    float* __restrict__ out, int n)
{
    __shared__ unsigned short wlds[16384];
    const int k = blockIdx.y;
    const int m0 = blockIdx.x * 256;
    {
        const bf16x8* src = (const bf16x8*)(Wb + (size_t)k * 16384);
        bf16x8* dst = (bf16x8*)wlds;
        for (int i = threadIdx.x; i < 2048; i += 512) dst[i] = src[i];
    }
    __syncthreads();
    const int wave = threadIdx.x >> 6;
    const int lane = threadIdx.x & 63;
    const int kg = lane >> 4;
    const int l15 = lane & 15;
    const int* iin  = idx_in  + (size_t)k * n;
    const int* iout = idx_out + (size_t)k * n;
    const int mbase = m0 + wave * 32;
    int arow0, arow1;
    { int m = mbase + l15;      arow0 = (m < n) ? iin[m] : 0; }
    { int m = mbase + 16 + l15; arow1 = (m < n) ? iin[m] : 0; }
    f32x4 acc[2][8];
#pragma unroll
    for (int s = 0; s < 2; ++s)
#pragma unroll
        for (int c = 0; c < 8; ++c) acc[s][c] = (f32x4){0.f, 0.f, 0.f, 0.f};
#pragma unroll
    for (int kk = 0; kk < 4; ++kk) {
        bf16x8 a0 = *(const bf16x8*)(xin + (size_t)arow0 * 128 + kk * 32 + kg * 8);
        bf16x8 a1 = *(const bf16x8*)(xin + (size_t)arow1 * 128 + kk * 32 + kg * 8);
#pragma unroll
        for (int c = 0; c < 8; ++c) {
            bf16x8 b = *(const bf16x8*)(wlds + ((kk * 8 + c) * 64 + lane) * 8);
            acc[0][c] = __builtin_amdgcn_mfma_f32_16x16x32_bf16(a0, b, acc[0][c], 0, 0, 0);
            acc[1][c] = __builtin_amdgcn_mfma_f32_16x16x32_bf16(a1, b, acc[1][c], 0, 0, 0);
        }
    }
#pragma unroll
    for (int s = 0; s < 2; ++s)
#pragma unroll
        for (int j = 0; j < 4; ++j) {
            int m = mbase + s * 16 + kg * 4 + j;
            if (m < n) {
                long orow = iout[m];
                float* dst = out + orow * 128 + l15;
#pragma unroll
                for (int c = 0; c < 8; ++c) atomicAdd(dst + c * 16, acc[s][c][j]);
            }
        }
}

// ---------------- BN epilogues (true layout f32 h) ----------------

__global__ void bn_stats(const float* __restrict__ h, float* __restrict__ stats, int n) {
    const int c = threadIdx.x & 127;
    const int half = threadIdx.x >> 7;
    const int r0 = blockIdx.x * 256;
    const int rend = min(r0 + 256, n);
    float s = 0.f, s2 = 0.f;
    for (int r = r0 + half; r < rend; r += 2) {
        float v = h[(size_t)r * 128 + c];
        s += v; s2 += v * v;
    }
    __shared__ float ls[256], ls2[256];
    ls[threadIdx.x] = s; ls2[threadIdx.x] = s2;
    __syncthreads();
    if (half == 0) {
        atomicAdd(&stats[c], ls[c] + ls[128 + c]);
        atomicAdd(&stats[128 + c], ls2[c] + ls2[128 + c]);
    }
}

__global__ void bn_finalize(float* stats, const float* __restrict__ g,
                            const float* __restrict__ b, float inv_n) {
    int c = threadIdx.x;  // 128 threads
    float mu = stats[c] * inv_n;
    float var = fmaxf(stats[128 + c] * inv_n - mu * mu, 0.f);
    float sc = g[c] * rsqrtf(var + 1e-5f);
    stats[256 + c] = sc;
    stats[384 + c] = b[c] - mu * sc;
}

__global__ void bn_relu_bf16(const float* __restrict__ h, const float* __restrict__ stats,
                             unsigned short* __restrict__ hb, long total) {
    long i = ((long)blockIdx.x * 256 + threadIdx.x) * 4;
    if (i >= total) return;
    int c = (int)(i & 127);
    f32x4 v = *(const f32x4*)(h + i);
    u16x4 r;
#pragma unroll
    for (int t = 0; t < 4; ++t) {
        float y = fmaxf(v[t] * stats[256 + c + t] + stats[384 + c + t], 0.f);
        r[t] = f2b(y);
    }
    *(u16x4*)(hb + i) = r;
}

__global__ void bn_res_relu(float* __restrict__ out, const float* __restrict__ stats,
                            const float* __restrict__ x, long total) {
    long i = ((long)blockIdx.x * 256 + threadIdx.x) * 4;
    if (i >= total) return;
    int c = (int)(i & 127);
    f32x4 h = *(const f32x4*)(out + i);
    f32x4 xv = *(const f32x4*)(x + i);
    f32x4 r;
#pragma unroll
    for (int t = 0; t < 4; ++t)
        r[t] = fmaxf(h[t] * stats[256 + c + t] + stats[384 + c + t] + xv[t], 0.f);
    *(f32x4*)(out + i) = r;
}

extern "C" void kernel_launch(void* const* d_in, const int* in_sizes, int n_in,
                              void* d_out, int out_size, void* d_ws, size_t ws_size,
                              hipStream_t stream) {
    const float* x  = (const float*)d_in[0];
    const float* W1 = (const float*)d_in[1];
    const float* g1 = (const float*)d_in[2];
    const float* b1 = (const float*)d_in[3];
    const float* W2 = (const float*)d_in[4];
    const float* g2 = (const float*)d_in[5];
    const float* b2 = (const float*)d_in[6];
    const int* idx_in  = (const int*)d_in[7];
    const int* idx_out = (const int*)d_in[8];

    const int n = in_sizes[0] / 128;
    const int K = in_sizes[1] / 16384;
    const long total = (long)n * 128;
    const int nk = K * n;
    float* acc = (float*)d_out;               // f32 h accumulator lives in d_out

    char* ws = (char*)d_ws;
    auto align256 = [](size_t v) { return (v + 255) & ~255ULL; };

    // fixed allocations
    size_t off = 0;
    const size_t o_slabA = off; off = align256(off + (size_t)total * 2);
    const size_t o_Wb1   = off; off = align256(off + (size_t)K * 16384 * 2);
    const size_t o_Wb2   = off; off = align256(off + (size_t)K * 16384 * 2);
    const size_t o_stats = off; off = align256(off + 1024 * 4);
    const size_t o_slot  = off; off = align256(off + (size_t)nk * 4);
    const size_t fixed_end = off;

    // choose largest k-group size that fits
    int gs = 0, G = 0;
    for (int cand = K; cand >= 1; --cand) {
        int gc = (K + cand - 1) / cand;
        size_t nbins = (size_t)n * gc;
        size_t nb = (nbins + 4095) / 4096;
        size_t need = fixed_end;
        need = align256(need + nbins * 4);          // cnt
        need = align256(need + (nbins + 1) * 4);    // row_ptr
        need = align256(need + nbins * 4);          // pos
        need = align256(need + (nb + 2) * 4);       // bsum
        need += (size_t)cand * (size_t)n * 256;     // y
        if (need <= ws_size) { gs = cand; G = gc; break; }
    }

    unsigned short* slabA = (unsigned short*)(ws + o_slabA);
    unsigned short* Wb1   = (unsigned short*)(ws + o_Wb1);
    unsigned short* Wb2   = (unsigned short*)(ws + o_Wb2);
    float* stats          = (float*)(ws + o_stats);
    int* slot             = (int*)(ws + o_slot);

    const dim3 b256(256);
    const int gCvt = (int)((total / 4 + 255) / 256);
    const int kelems = K * 16384;

    hipLaunchKernelGGL(zero_f32, dim3(1), b256, 0, stream, stats, (long)1024);
    hipLaunchKernelGGL(cvt_bf16, dim3(gCvt), b256, 0, stream, x, slabA, total);
    hipLaunchKernelGGL(prep_w, dim3((2 * kelems + 255) / 256), b256, 0, stream,
                       W1, W2, Wb1, Wb2, kelems);

    if (gs > 0) {
        size_t nbins = (size_t)n * G;
        size_t nb = (nbins + 4095) / 4096;
        off = fixed_end;
        int* cnt     = (int*)(ws + off); off = align256(off + nbins * 4);
        int* row_ptr = (int*)(ws + off); off = align256(off + (nbins + 1) * 4);
        int* pos     = (int*)(ws + off); off = align256(off + nbins * 4);
        int* bsum    = (int*)(ws + off); off = align256(off + (nb + 2) * 4);
        unsigned* yu = (unsigned*)(ws + off);
        const int gsn = gs * n;

        // CSR build (bins g-major), shared by both convs
        hipLaunchKernelGGL(zero_f32, dim3((int)(((nbins + 3) / 4 + 255) / 256)), b256, 0, stream,
                           (float*)cnt, (long)nbins);
        hipLaunchKernelGGL(hist_k, dim3((nk + 255) / 256), b256, 0, stream,
                           idx_out, cnt, nk, gsn, n, G);
        hipLaunchKernelGGL(scan_part, dim3((int)nb), b256, 0, stream, cnt, bsum, (int)nbins);
        hipLaunchKernelGGL(scan_bsum, dim3(1), dim3(64), 0, stream, bsum, (int)nb, row_ptr, (int)nbins);
        hipLaunchKernelGGL(scan_final, dim3((int)nb), b256, 0, stream, cnt, bsum, row_ptr, pos, (int)nbins);
        hipLaunchKernelGGL(fill_slot, dim3((nk + 255) / 256), b256, 0, stream,
                           idx_out, pos, slot, nk, gsn, n, G);

        for (int conv = 0; conv < 2; ++conv) {
            const unsigned short* Wb = conv ? Wb2 : Wb1;
            float* st = stats + conv * 512;
            for (int g = 0; g < G; ++g) {
                int ks = min(gs, K - g * gs);
                hipLaunchKernelGGL(gemm_y, dim3((n + 255) / 256, ks), dim3(512), 0, stream,
                                   slabA, Wb + (size_t)g * gs * 16384,
                                   idx_in + (size_t)g * gsn, slot + (size_t)g * gsn, yu, n);
                hipLaunchKernelGGL(reduce_y, dim3(2048), b256, 0, stream,
                                   yu, row_ptr + (size_t)g * n, acc, st,
                                   n, g * gsn, (g > 0) ? 1 : 0,
                                   (G == 1 || g == G - 1) ? (G == 1 ? 1 : 0) : 0);
            }
            if (G > 1)
                hipLaunchKernelGGL(bn_stats, dim3((n + 255) / 256), b256, 0, stream, acc, st, n);
            hipLaunchKernelGGL(bn_finalize, dim3(1), dim3(128), 0, stream, st,
                               conv ? g2 : g1, conv ? b2 : b1, 1.0f / n);
            if (conv == 0)
                hipLaunchKernelGGL(bn_relu_bf16, dim3(gCvt), b256, 0, stream, acc, st, slabA, total);
            else
                hipLaunchKernelGGL(bn_res_relu, dim3(gCvt), b256, 0, stream, acc, st, x, total);
        }
    } else {
        for (int conv = 0; conv < 2; ++conv) {
            const unsigned short* Wb = conv ? Wb2 : Wb1;
            float* st = stats + conv * 512;
            hipLaunchKernelGGL(zero_f32, dim3(gCvt), b256, 0, stream, acc, total);
            hipLaunchKernelGGL(conv_atomic, dim3((n + 255) / 256, K), dim3(512), 0, stream,
                               slabA, Wb, idx_in, idx_out, acc, n);
            hipLaunchKernelGGL(bn_stats, dim3((n + 255) / 256), b256, 0, stream, acc, st, n);
            hipLaunchKernelGGL(bn_finalize, dim3(1), dim3(128), 0, stream, st,
                               conv ? g2 : g1, conv ? b2 : b1, 1.0f / n);
            if (conv == 0)
                hipLaunchKernelGGL(bn_relu_bf16, dim3(gCvt), b256, 0, stream, acc, st, slabA, total);
            else
                hipLaunchKernelGGL(bn_res_relu, dim3(gCvt), b256, 0, stream, acc, st, x, total);
        }
    }
}

// Round 5
// 1295.476 us; speedup vs baseline: 3.6323x; 1.1056x over previous
//
#include <hip/hip_runtime.h>

typedef __attribute__((ext_vector_type(8))) short bf16x8;
typedef __attribute__((ext_vector_type(4))) float f32x4;
typedef __attribute__((ext_vector_type(4))) unsigned short u16x4;
typedef __attribute__((ext_vector_type(4))) unsigned u32x4;

__device__ __forceinline__ unsigned short f2b(float f) {
    unsigned u = __builtin_bit_cast(unsigned, f);
    u += 0x7fffu + ((u >> 16) & 1u);   // round-to-nearest-even
    return (unsigned short)(u >> 16);
}

__global__ void zero_f32(float* __restrict__ p, long total) {
    long i = ((long)blockIdx.x * blockDim.x + threadIdx.x) * 4;
    if (i + 3 < total) {
        *(f32x4*)(p + i) = (f32x4){0.f, 0.f, 0.f, 0.f};
    } else {
        for (long t = i; t < total; ++t) p[t] = 0.f;
    }
}

__global__ void cvt_bf16(const float* __restrict__ x, unsigned short* __restrict__ o, long total) {
    long i = ((long)blockIdx.x * blockDim.x + threadIdx.x) * 4;
    if (i >= total) return;
    f32x4 v = *(const f32x4*)(x + i);
    u16x4 r;
#pragma unroll
    for (int t = 0; t < 4; ++t) r[t] = f2b(v[t]);
    *(u16x4*)(o + i) = r;
}

// Wb[k][frag f=kk*8+c][lane][j] = W[k][cin=kk*32+(lane>>4)*8+j][cout=c*16+(lane&15)]
__global__ void prep_w(const float* __restrict__ W1, const float* __restrict__ W2,
                       unsigned short* __restrict__ Wb1, unsigned short* __restrict__ Wb2,
                       int kelems) {
    int tid = blockIdx.x * 256 + threadIdx.x;
    if (tid >= 2 * kelems) return;
    int which = (tid >= kelems) ? 1 : 0;
    int rem = which ? (tid - kelems) : tid;
    int k = rem >> 14;
    int r2 = rem & 16383;
    int f = r2 >> 9;
    int lane = (r2 >> 3) & 63;
    int j = r2 & 7;
    int kk = f >> 3, c = f & 7;
    int cin = kk * 32 + (lane >> 4) * 8 + j;
    int cout = c * 16 + (lane & 15);
    const float* W = which ? W2 : W1;
    unsigned short* Wb = which ? Wb2 : Wb1;
    Wb[rem] = f2b(W[(size_t)k * 16384 + cin * 128 + cout]);
}

// ---------------- CSR build: bins g-major (bin = g*n + r), cnt padded 1 bin / 64B line ----------------

// single atomic pass: rank[t] = running count of bin. rank stored LINEARLY in slot[].
__global__ void hist_rank(const int* __restrict__ io, int* __restrict__ cnt,
                          int* __restrict__ rank, int nk, int gsn, int n, int G) {
    int t = blockIdx.x * 256 + threadIdx.x;
    if (t >= nk) return;
    int r = io[t];
    int g = (G == 1) ? 0 : (t / gsn);
    rank[t] = atomicAdd(&cnt[((size_t)g * n + r) << 4], 1);
}

__global__ void scan_part(const int* __restrict__ cnt, int* __restrict__ bsum, int nbins) {
    __shared__ int ls[256];
    int base = blockIdx.x * 4096 + threadIdx.x * 16;
    int s = 0;
#pragma unroll
    for (int i = 0; i < 16; ++i) { int idx = base + i; if (idx < nbins) s += cnt[(size_t)idx << 4]; }
    ls[threadIdx.x] = s; __syncthreads();
    for (int o = 128; o > 0; o >>= 1) {
        if ((int)threadIdx.x < o) ls[threadIdx.x] += ls[threadIdx.x + o];
        __syncthreads();
    }
    if (threadIdx.x == 0) bsum[blockIdx.x] = ls[0];
}

__global__ void scan_bsum(int* __restrict__ bsum, int nb, int* __restrict__ row_ptr, int nbins) {
    if (threadIdx.x == 0 && blockIdx.x == 0) {
        int run = 0;
        for (int i = 0; i < nb; ++i) { int t = bsum[i]; bsum[i] = run; run += t; }
        row_ptr[nbins] = run;
    }
}

__global__ void scan_final(const int* __restrict__ cnt, const int* __restrict__ bsum,
                           int* __restrict__ row_ptr, int nbins) {
    __shared__ int ls[256];
    const int tid = threadIdx.x;
    int base = blockIdx.x * 4096 + tid * 16;
    int loc[16];
    int s = 0;
#pragma unroll
    for (int i = 0; i < 16; ++i) {
        int idx = base + i;
        int v = (idx < nbins) ? cnt[(size_t)idx << 4] : 0;
        loc[i] = s; s += v;
    }
    ls[tid] = s; __syncthreads();
    for (int o = 1; o < 256; o <<= 1) {
        int add = (tid >= o) ? ls[tid - o] : 0;
        __syncthreads();
        ls[tid] += add;
        __syncthreads();
    }
    int excl = ls[tid] - s + bsum[blockIdx.x];
#pragma unroll
    for (int i = 0; i < 16; ++i) {
        int idx = base + i;
        if (idx < nbins) row_ptr[idx] = excl + loc[i];
    }
}

// slot[t] = row_ptr[bin] + rank[t] - group_base. NO atomics, linear RMW of slot[].
__global__ void slot_from_rank(const int* __restrict__ io, const int* __restrict__ row_ptr,
                               int* __restrict__ slot, int nk, int gsn, int n, int G) {
    int t = blockIdx.x * 256 + threadIdx.x;
    if (t >= nk) return;
    int r = io[t];
    int g = (G == 1) ? 0 : (t / gsn);
    slot[t] = row_ptr[(size_t)g * n + r] + slot[t] - g * gsn;
}

// ---------------- Phase A: gathered GEMM -> y rows at CSR slots (L3-resident, plain stores) --------
// y row = 64 u32; u32 index (l15*4+cp) holds true cols (l15+32cp, l15+32cp+16).
__global__ __launch_bounds__(512) void gemm_y(
    const unsigned short* __restrict__ xin,   // [n,128] bf16 true layout
    const unsigned short* __restrict__ Wb,    // group base
    const int* __restrict__ idx_in,           // group base [ks,n]
    const int* __restrict__ slot,             // group base [ks*n], group-local positions
    unsigned* __restrict__ yu,                // [gs*n, 64]
    int n)
{
    __shared__ unsigned short wlds[16384];
    __shared__ int sslot[256];
    const int k = blockIdx.y;
    const int m0 = blockIdx.x * 256;

    {
        const bf16x8* src = (const bf16x8*)(Wb + (size_t)k * 16384);
        bf16x8* dst = (bf16x8*)wlds;
        for (int i = threadIdx.x; i < 2048; i += 512) dst[i] = src[i];
        if (threadIdx.x < 256) {
            int m = m0 + threadIdx.x;
            sslot[threadIdx.x] = (m < n) ? slot[(size_t)k * n + m] : 0;
        }
    }
    __syncthreads();

    const int wave = threadIdx.x >> 6;
    const int lane = threadIdx.x & 63;
    const int kg = lane >> 4;
    const int l15 = lane & 15;

    const int* iin = idx_in + (size_t)k * n;
    const int mbase = m0 + wave * 32;

    int arow0, arow1;
    { int m = mbase + l15;      arow0 = (m < n) ? iin[m] : 0; }
    { int m = mbase + 16 + l15; arow1 = (m < n) ? iin[m] : 0; }

    f32x4 acc[2][8];
#pragma unroll
    for (int s = 0; s < 2; ++s)
#pragma unroll
        for (int c = 0; c < 8; ++c) acc[s][c] = (f32x4){0.f, 0.f, 0.f, 0.f};

#pragma unroll
    for (int kk = 0; kk < 4; ++kk) {
        bf16x8 a0 = *(const bf16x8*)(xin + (size_t)arow0 * 128 + kk * 32 + kg * 8);
        bf16x8 a1 = *(const bf16x8*)(xin + (size_t)arow1 * 128 + kk * 32 + kg * 8);
#pragma unroll
        for (int c = 0; c < 8; ++c) {
            bf16x8 b = *(const bf16x8*)(wlds + ((kk * 8 + c) * 64 + lane) * 8);
            acc[0][c] = __builtin_amdgcn_mfma_f32_16x16x32_bf16(a0, b, acc[0][c], 0, 0, 0);
            acc[1][c] = __builtin_amdgcn_mfma_f32_16x16x32_bf16(a1, b, acc[1][c], 0, 0, 0);
        }
    }

    // value acc[s][c][j]: gathered row m = mbase+s*16+kg*4+j, true col l15+16c
#pragma unroll
    for (int s = 0; s < 2; ++s) {
#pragma unroll
        for (int j = 0; j < 4; ++j) {
            int m = mbase + s * 16 + kg * 4 + j;
            if (m < n) {
                u32x4 v;
#pragma unroll
                for (int cp = 0; cp < 4; ++cp) {
                    unsigned pk;
                    asm("v_cvt_pk_bf16_f32 %0, %1, %2"
                        : "=v"(pk)
                        : "v"(acc[s][2 * cp][j]), "v"(acc[s][2 * cp + 1][j]));
                    v[cp] = pk;
                }
                int p = sslot[m - m0];
                *(u32x4*)(yu + (size_t)p * 64 + l15 * 4) = v;   // plain store -> L3-resident
            }
        }
    }
}

// ---------------- Phase B: contiguous segment reduce (+ fused BN stats on last group) -------------
// lane l owns u32 column l: true cols tc0 = (l>>2)+32*(l&3) and tc0+16.
__global__ __launch_bounds__(256) void reduce_y(
    const unsigned* __restrict__ yu,
    const int* __restrict__ rp,        // row_ptr + g*n
    float* __restrict__ hbuf,          // [n,128] f32, true layout
    float* __restrict__ stats,
    int n, int base, int accum, int do_stats)
{
    const int w = threadIdx.x >> 6, l = threadIdx.x & 63;
    const int tc0 = (l >> 2) + 32 * (l & 3);
    float s0 = 0.f, q0 = 0.f, s1 = 0.f, q1 = 0.f;

    for (int r = blockIdx.x * 4 + w; r < n; r += gridDim.x * 4) {
        int e = rp[r] - base;
        const int e1 = rp[r + 1] - base;
        float a0 = 0.f, a1 = 0.f;
        for (; e < e1; ++e) {
            unsigned v = yu[(size_t)e * 64 + l];
            a0 += __builtin_bit_cast(float, v << 16);
            a1 += __builtin_bit_cast(float, v & 0xffff0000u);
        }
        float* dst = hbuf + (size_t)r * 128 + tc0;
        if (accum) { a0 += dst[0]; a1 += dst[16]; }
        dst[0] = a0; dst[16] = a1;
        if (do_stats) { s0 += a0; q0 += a0 * a0; s1 += a1; q1 += a1 * a1; }
    }

    if (do_stats) {
        __shared__ float ls[4][64][4];
        ls[w][l][0] = s0; ls[w][l][1] = q0; ls[w][l][2] = s1; ls[w][l][3] = q1;
        __syncthreads();
        if (w == 0) {
            float t0 = 0, t1 = 0, t2 = 0, t3 = 0;
#pragma unroll
            for (int ww = 0; ww < 4; ++ww) {
                t0 += ls[ww][l][0]; t1 += ls[ww][l][1];
                t2 += ls[ww][l][2]; t3 += ls[ww][l][3];
            }
            atomicAdd(&stats[tc0], t0);       atomicAdd(&stats[128 + tc0], t1);
            atomicAdd(&stats[tc0 + 16], t2);  atomicAdd(&stats[128 + tc0 + 16], t3);
        }
    }
}

// ---------------- Fallback: atomic conv (R1) ----------------
__global__ __launch_bounds__(512) void conv_atomic(
    const unsigned short* __restrict__ xin, const unsigned short* __restrict__ Wb,
    const int* __restrict__ idx_in, const int* __restrict__ idx_out,
    float* __restrict__ out, int n)
{
    __shared__ unsigned short wlds[16384];
    const int k = blockIdx.y;
    const int m0 = blockIdx.x * 256;
    {
        const bf16x8* src = (const bf16x8*)(Wb + (size_t)k * 16384);
        bf16x8* dst = (bf16x8*)wlds;
        for (int i = threadIdx.x; i < 2048; i += 512) dst[i] = src[i];
    }
    __syncthreads();
    const int wave = threadIdx.x >> 6;
    const int lane = threadIdx.x & 63;
    const int kg = lane >> 4;
    const int l15 = lane & 15;
    const int* iin  = idx_in  + (size_t)k * n;
    const int* iout = idx_out + (size_t)k * n;
    const int mbase = m0 + wave * 32;
    int arow0, arow1;
    { int m = mbase + l15;      arow0 = (m < n) ? iin[m] : 0; }
    { int m = mbase + 16 + l15; arow1 = (m < n) ? iin[m] : 0; }
    f32x4 acc[2][8];
#pragma unroll
    for (int s = 0; s < 2; ++s)
#pragma unroll
        for (int c = 0; c < 8; ++c) acc[s][c] = (f32x4){0.f, 0.f, 0.f, 0.f};
#pragma unroll
    for (int kk = 0; kk < 4; ++kk) {
        bf16x8 a0 = *(const bf16x8*)(xin + (size_t)arow0 * 128 + kk * 32 + kg * 8);
        bf16x8 a1 = *(const bf16x8*)(xin + (size_t)arow1 * 128 + kk * 32 + kg * 8);
#pragma unroll
        for (int c = 0; c < 8; ++c) {
            bf16x8 b = *(const bf16x8*)(wlds + ((kk * 8 + c) * 64 + lane) * 8);
            acc[0][c] = __builtin_amdgcn_mfma_f32_16x16x32_bf16(a0, b, acc[0][c], 0, 0, 0);
            acc[1][c] = __builtin_amdgcn_mfma_f32_16x16x32_bf16(a1, b, acc[1][c], 0, 0, 0);
        }
    }
#pragma unroll
    for (int s = 0; s < 2; ++s)
#pragma unroll
        for (int j = 0; j < 4; ++j) {
            int m = mbase + s * 16 + kg * 4 + j;
            if (m < n) {
                long orow = iout[m];
                float* dst = out + orow * 128 + l15;
#pragma unroll
                for (int c = 0; c < 8; ++c) atomicAdd(dst + c * 16, acc[s][c][j]);
            }
        }
}

// ---------------- BN epilogues (true layout f32 h) ----------------

__global__ void bn_stats(const float* __restrict__ h, float* __restrict__ stats, int n) {
    const int c = threadIdx.x & 127;
    const int half = threadIdx.x >> 7;
    const int r0 = blockIdx.x * 256;
    const int rend = min(r0 + 256, n);
    float s = 0.f, s2 = 0.f;
    for (int r = r0 + half; r < rend; r += 2) {
        float v = h[(size_t)r * 128 + c];
        s += v; s2 += v * v;
    }
    __shared__ float ls[256], ls2[256];
    ls[threadIdx.x] = s; ls2[threadIdx.x] = s2;
    __syncthreads();
    if (half == 0) {
        atomicAdd(&stats[c], ls[c] + ls[128 + c]);
        atomicAdd(&stats[128 + c], ls2[c] + ls2[128 + c]);
    }
}

__global__ void bn_finalize(float* stats, const float* __restrict__ g,
                            const float* __restrict__ b, float inv_n) {
    int c = threadIdx.x;  // 128 threads
    float mu = stats[c] * inv_n;
    float var = fmaxf(stats[128 + c] * inv_n - mu * mu, 0.f);
    float sc = g[c] * rsqrtf(var + 1e-5f);
    stats[256 + c] = sc;
    stats[384 + c] = b[c] - mu * sc;
}

__global__ void bn_relu_bf16(const float* __restrict__ h, const float* __restrict__ stats,
                             unsigned short* __restrict__ hb, long total) {
    long i = ((long)blockIdx.x * 256 + threadIdx.x) * 4;
    if (i >= total) return;
    int c = (int)(i & 127);
    f32x4 v = *(const f32x4*)(h + i);
    u16x4 r;
#pragma unroll
    for (int t = 0; t < 4; ++t) {
        float y = fmaxf(v[t] * stats[256 + c + t] + stats[384 + c + t], 0.f);
        r[t] = f2b(y);
    }
    *(u16x4*)(hb + i) = r;
}

__global__ void bn_res_relu(float* __restrict__ out, const float* __restrict__ stats,
                            const float* __restrict__ x, long total) {
    long i = ((long)blockIdx.x * 256 + threadIdx.x) * 4;
    if (i >= total) return;
    int c = (int)(i & 127);
    f32x4 h = *(const f32x4*)(out + i);
    f32x4 xv = *(const f32x4*)(x + i);
    f32x4 r;
#pragma unroll
    for (int t = 0; t < 4; ++t)
        r[t] = fmaxf(h[t] * stats[256 + c + t] + stats[384 + c + t] + xv[t], 0.f);
    *(f32x4*)(out + i) = r;
}

extern "C" void kernel_launch(void* const* d_in, const int* in_sizes, int n_in,
                              void* d_out, int out_size, void* d_ws, size_t ws_size,
                              hipStream_t stream) {
    const float* x  = (const float*)d_in[0];
    const float* W1 = (const float*)d_in[1];
    const float* g1 = (const float*)d_in[2];
    const float* b1 = (const float*)d_in[3];
    const float* W2 = (const float*)d_in[4];
    const float* g2 = (const float*)d_in[5];
    const float* b2 = (const float*)d_in[6];
    const int* idx_in  = (const int*)d_in[7];
    const int* idx_out = (const int*)d_in[8];

    const int n = in_sizes[0] / 128;
    const int K = in_sizes[1] / 16384;
    const long total = (long)n * 128;
    const int nk = K * n;
    float* acc = (float*)d_out;               // f32 h accumulator lives in d_out

    char* ws = (char*)d_ws;
    auto align256 = [](size_t v) { return (v + 255) & ~255ULL; };

    // fixed allocations
    size_t off = 0;
    const size_t o_slabA = off; off = align256(off + (size_t)total * 2);
    const size_t o_Wb1   = off; off = align256(off + (size_t)K * 16384 * 2);
    const size_t o_Wb2   = off; off = align256(off + (size_t)K * 16384 * 2);
    const size_t o_stats = off; off = align256(off + 1024 * 4);
    const size_t o_slot  = off; off = align256(off + (size_t)nk * 4);
    const size_t fixed_end = off;

    // choose largest k-group size that fits, CAPPED at 5 so y (gs*n*256B) stays L3-resident
    const int gs_cap = (K < 5) ? K : 5;
    int gs = 0, G = 0;
    for (int cand = gs_cap; cand >= 1; --cand) {
        int gc = (K + cand - 1) / cand;
        size_t nbins = (size_t)n * gc;
        size_t nb = (nbins + 4095) / 4096;
        size_t need = fixed_end;
        need = align256(need + nbins * 64);         // cnt (padded 1 bin / 64B)
        need = align256(need + (nbins + 1) * 4);    // row_ptr
        need = align256(need + (nb + 2) * 4);       // bsum
        need += (size_t)cand * (size_t)n * 256;     // y
        if (need <= ws_size) { gs = cand; G = gc; break; }
    }

    unsigned short* slabA = (unsigned short*)(ws + o_slabA);
    unsigned short* Wb1   = (unsigned short*)(ws + o_Wb1);
    unsigned short* Wb2   = (unsigned short*)(ws + o_Wb2);
    float* stats          = (float*)(ws + o_stats);
    int* slot             = (int*)(ws + o_slot);

    const dim3 b256(256);
    const int gCvt = (int)((total / 4 + 255) / 256);
    const int kelems = K * 16384;

    hipLaunchKernelGGL(zero_f32, dim3(1), b256, 0, stream, stats, (long)1024);
    hipLaunchKernelGGL(cvt_bf16, dim3(gCvt), b256, 0, stream, x, slabA, total);
    hipLaunchKernelGGL(prep_w, dim3((2 * kelems + 255) / 256), b256, 0, stream,
                       W1, W2, Wb1, Wb2, kelems);

    if (gs > 0) {
        size_t nbins = (size_t)n * G;
        size_t nb = (nbins + 4095) / 4096;
        off = fixed_end;
        int* cnt     = (int*)(ws + off); off = align256(off + nbins * 64);
        int* row_ptr = (int*)(ws + off); off = align256(off + (nbins + 1) * 4);
        int* bsum    = (int*)(ws + off); off = align256(off + (nb + 2) * 4);
        unsigned* yu = (unsigned*)(ws + off);
        const int gsn = gs * n;

        // CSR build: ONE atomic pass (hist_rank), then scan, then linear slot pass
        hipLaunchKernelGGL(zero_f32, dim3((int)((nbins * 16 / 4 + 255) / 256) + 1), b256, 0, stream,
                           (float*)cnt, (long)(nbins * 16));
        hipLaunchKernelGGL(hist_rank, dim3((nk + 255) / 256), b256, 0, stream,
                           idx_out, cnt, slot, nk, gsn, n, G);
        hipLaunchKernelGGL(scan_part, dim3((int)nb), b256, 0, stream, cnt, bsum, (int)nbins);
        hipLaunchKernelGGL(scan_bsum, dim3(1), dim3(64), 0, stream, bsum, (int)nb, row_ptr, (int)nbins);
        hipLaunchKernelGGL(scan_final, dim3((int)nb), b256, 0, stream, cnt, bsum, row_ptr, (int)nbins);
        hipLaunchKernelGGL(slot_from_rank, dim3((nk + 255) / 256), b256, 0, stream,
                           idx_out, row_ptr, slot, nk, gsn, n, G);

        for (int conv = 0; conv < 2; ++conv) {
            const unsigned short* Wb = conv ? Wb2 : Wb1;
            float* st = stats + conv * 512;
            for (int g = 0; g < G; ++g) {
                int ks = min(gs, K - g * gs);
                hipLaunchKernelGGL(gemm_y, dim3((n + 255) / 256, ks), dim3(512), 0, stream,
                                   slabA, Wb + (size_t)g * gs * 16384,
                                   idx_in + (size_t)g * gsn, slot + (size_t)g * gsn, yu, n);
                hipLaunchKernelGGL(reduce_y, dim3(2048), b256, 0, stream,
                                   yu, row_ptr + (size_t)g * n, acc, st,
                                   n, g * gsn, (g > 0) ? 1 : 0, (g == G - 1) ? 1 : 0);
            }
            hipLaunchKernelGGL(bn_finalize, dim3(1), dim3(128), 0, stream, st,
                               conv ? g2 : g1, conv ? b2 : b1, 1.0f / n);
            if (conv == 0)
                hipLaunchKernelGGL(bn_relu_bf16, dim3(gCvt), b256, 0, stream, acc, st, slabA, total);
            else
                hipLaunchKernelGGL(bn_res_relu, dim3(gCvt), b256, 0, stream, acc, st, x, total);
        }
    } else {
        for (int conv = 0; conv < 2; ++conv) {
            const unsigned short* Wb = conv ? Wb2 : Wb1;
            float* st = stats + conv * 512;
            hipLaunchKernelGGL(zero_f32, dim3(gCvt), b256, 0, stream, acc, total);
            hipLaunchKernelGGL(conv_atomic, dim3((n + 255) / 256, K), dim3(512), 0, stream,
                               slabA, Wb, idx_in, idx_out, acc, n);
            hipLaunchKernelGGL(bn_stats, dim3((n + 255) / 256), b256, 0, stream, acc, st, n);
            hipLaunchKernelGGL(bn_finalize, dim3(1), dim3(128), 0, stream, st,
                               conv ? g2 : g1, conv ? b2 : b1, 1.0f / n);
            if (conv == 0)
                hipLaunchKernelGGL(bn_relu_bf16, dim3(gCvt), b256, 0, stream, acc, st, slabA, total);
            else
                hipLaunchKernelGGL(bn_res_relu, dim3(gCvt), b256, 0, stream, acc, st, x, total);
        }
    }
}